// Round 2
// baseline (406.118 us; speedup 1.0000x reference)
//
#include <hip/hip_runtime.h>

typedef unsigned int uint;
typedef unsigned short ushort;
typedef __attribute__((ext_vector_type(8))) short bf16x8;
typedef __attribute__((ext_vector_type(4))) float f32x4;

// ---------------- compile-time Clifford tables (replicates reference numpy) --------
struct GPTables {
    signed char jid[16][16];   // output component index j for pair (i,k)
    float       sgn[16][16];   // Cayley sign
    signed char pid[16][16];   // path index into gp_weight[n, 35]
    float       beta[16];
    signed char grade[16];
};

constexpr int popc4(int x) { return ((x >> 0) & 1) + ((x >> 1) & 1) + ((x >> 2) & 1) + ((x >> 3) & 1); }

constexpr GPTables make_tables() {
    GPTables T{};
    int blades[16] = {0, 1, 2, 4, 8, 3, 5, 6, 9, 10, 12, 7, 11, 13, 14, 15};
    int idxof[16] = {};
    for (int i = 0; i < 16; ++i) idxof[blades[i]] = i;
    float metric[4] = {1.f, -1.f, -1.f, -1.f};
    for (int i = 0; i < 16; ++i) {
        T.grade[i] = (signed char)popc4(blades[i]);
        float b = 1.f;
        for (int bit = 0; bit < 4; ++bit)
            if ((blades[i] >> bit) & 1) b *= metric[bit];
        T.beta[i] = b;
    }
    bool paths[5][5][5] = {};
    for (int a = 0; a < 16; ++a)
        for (int b = 0; b < 16; ++b)
            paths[popc4(a)][popc4(a ^ b)][popc4(b)] = true;
    int pid3[5][5][5] = {};
    int cnt = 0;
    for (int gi = 0; gi < 5; ++gi)
        for (int gj = 0; gj < 5; ++gj)
            for (int gk = 0; gk < 5; ++gk)
                if (paths[gi][gj][gk]) pid3[gi][gj][gk] = cnt++;
    for (int ii = 0; ii < 16; ++ii) {
        for (int kk = 0; kk < 16; ++kk) {
            int a = blades[ii], b = blades[kk];
            int c = a ^ b;
            int s = 0, t = a >> 1;
            while (t) { s += popc4(t & b); t >>= 1; }
            float sign = (s & 1) ? -1.f : 1.f;
            for (int bit = 0; bit < 4; ++bit)
                if (((a >> bit) & 1) && ((b >> bit) & 1)) sign *= metric[bit];
            T.jid[ii][kk] = (signed char)idxof[c];
            T.sgn[ii][kk] = sign;
            T.pid[ii][kk] = (signed char)pid3[popc4(a)][popc4(c)][popc4(b)];
        }
    }
    return T;
}

constexpr GPTables TBL = make_tables();
__constant__ signed char GRADE_OF_C[16] = {0, 1, 1, 1, 1, 2, 2, 2, 2, 2, 2, 3, 3, 3, 3, 4};

// sizes
#define BF (4096)
#define FF (512)
#define BM_ (2097152)  // BF*FF

__device__ inline ushort f2bf(float f) {
    uint u = __float_as_uint(f);
    uint r = (u + 0x7fffu + ((u >> 16) & 1u)) >> 16;
    return (ushort)r;
}
__device__ inline float bf2f(ushort h) { return __uint_as_float(((uint)h) << 16); }

// ---------------- kernel 1: transpose + split-cast x -> Xp_hi/Xp_lo [16][BM_] -------
__global__ __launch_bounds__(256) void k_transpose_x(const float* __restrict__ x,
                                                     ushort* __restrict__ Xh,
                                                     ushort* __restrict__ Xl) {
    const int p0 = (blockIdx.x * 256 + threadIdx.x) * 2;  // two consecutive (b,m) pairs
    float v[32];
    const float4* x4 = (const float4*)(x + (size_t)p0 * 16);
#pragma unroll
    for (int j = 0; j < 8; ++j) {
        float4 t = x4[j];
        v[j * 4 + 0] = t.x; v[j * 4 + 1] = t.y; v[j * 4 + 2] = t.z; v[j * 4 + 3] = t.w;
    }
#pragma unroll
    for (int i = 0; i < 16; ++i) {
        ushort h0 = f2bf(v[i]),      h1 = f2bf(v[16 + i]);
        ushort l0 = f2bf(v[i] - bf2f(h0));
        ushort l1 = f2bf(v[16 + i] - bf2f(h1));
        *(uint*)&Xh[(size_t)i * BM_ + p0] = (uint)h0 | ((uint)h1 << 16);
        *(uint*)&Xl[(size_t)i * BM_ + p0] = (uint)l0 | ((uint)l1 << 16);
    }
}

// ---------------- kernel 2: pack weights -> Wb[15][512][512] bf16 ------------------
// planes 0..4 = right_hi, 5..9 = right_lo, 10..14 = left_hi (per grade)
__global__ __launch_bounds__(256) void k_prep_w(const float* __restrict__ w_right,
                                                const float* __restrict__ w_left,
                                                ushort* __restrict__ Wb) {
    const int n = blockIdx.x;        // 0..511
    const int m = threadIdx.x * 2;
#pragma unroll
    for (int g = 0; g < 5; ++g) {
        float a = w_right[(size_t)n * (FF * 5) + (size_t)m * 5 + g];
        float b = w_right[(size_t)n * (FF * 5) + (size_t)(m + 1) * 5 + g];
        ushort ah = f2bf(a), bh = f2bf(b);
        ushort al = f2bf(a - bf2f(ah)), bl = f2bf(b - bf2f(bh));
        *(uint*)&Wb[(size_t)g * (FF * FF) + (size_t)n * FF + m] = (uint)ah | ((uint)bh << 16);
        *(uint*)&Wb[(size_t)(5 + g) * (FF * FF) + (size_t)n * FF + m] = (uint)al | ((uint)bl << 16);
        float c = w_left[(size_t)n * (FF * 5) + (size_t)m * 5 + g];
        float d = w_left[(size_t)n * (FF * 5) + (size_t)(m + 1) * 5 + g];
        *(uint*)&Wb[(size_t)(10 + g) * (FF * FF) + (size_t)n * FF + m] =
            (uint)f2bf(c) | ((uint)f2bf(d) << 16);
    }
}

// ---------------- kernel 3a: right GEMM, split precision (3 MFMA products) ---------
// C[comp][b][n] = sum_m x[b,m,comp] * w_right[n,m,grade(comp)]  (f32 out)
__global__ __launch_bounds__(256) void k_gemm_right(const ushort* __restrict__ Xh,
                                                    const ushort* __restrict__ Xl,
                                                    const ushort* __restrict__ Wb,
                                                    float* __restrict__ OutR) {
    const int comp = blockIdx.z;
    const ushort* Ah = Xh + (size_t)comp * BM_;
    const ushort* Al = Xl + (size_t)comp * BM_;
    const int g = GRADE_OF_C[comp];
    const ushort* Bh = Wb + (size_t)g * (FF * FF);
    const ushort* Bl = Wb + (size_t)(5 + g) * (FF * FF);
    float* C = OutR + (size_t)comp * BM_;
    const int m0 = blockIdx.x * 128;
    const int n0 = blockIdx.y * 128;

    __shared__ ushort Ahs[128][32], Als[128][32], Bhs[128][32], Bls[128][32];

    const int tid = threadIdx.x;
    const int lane = tid & 63, wid = tid >> 6;
    const int wm = wid >> 1, wn = wid & 1;
    const int lr = lane & 15, lk = (lane >> 4) * 8;

    f32x4 acc[4][4] = {};

    for (int k0 = 0; k0 < FF; k0 += 32) {
#pragma unroll
        for (int pass = 0; pass < 2; ++pass) {
            int q = tid + pass * 256;
            int row = q >> 2;
            int col = (q & 3) * 8;
            *(uint4*)&Ahs[row][col] = *(const uint4*)&Ah[(size_t)(m0 + row) * FF + k0 + col];
            *(uint4*)&Als[row][col] = *(const uint4*)&Al[(size_t)(m0 + row) * FF + k0 + col];
            *(uint4*)&Bhs[row][col] = *(const uint4*)&Bh[(size_t)(n0 + row) * FF + k0 + col];
            *(uint4*)&Bls[row][col] = *(const uint4*)&Bl[(size_t)(n0 + row) * FF + k0 + col];
        }
        __syncthreads();
        bf16x8 ah[4], al[4], bh[4], bl[4];
#pragma unroll
        for (int mb = 0; mb < 4; ++mb) {
            ah[mb] = *(const bf16x8*)&Ahs[wm * 64 + mb * 16 + lr][lk];
            al[mb] = *(const bf16x8*)&Als[wm * 64 + mb * 16 + lr][lk];
        }
#pragma unroll
        for (int nb = 0; nb < 4; ++nb) {
            bh[nb] = *(const bf16x8*)&Bhs[wn * 64 + nb * 16 + lr][lk];
            bl[nb] = *(const bf16x8*)&Bls[wn * 64 + nb * 16 + lr][lk];
        }
#pragma unroll
        for (int mb = 0; mb < 4; ++mb)
#pragma unroll
            for (int nb = 0; nb < 4; ++nb) {
                acc[mb][nb] = __builtin_amdgcn_mfma_f32_16x16x32_bf16(ah[mb], bh[nb], acc[mb][nb], 0, 0, 0);
                acc[mb][nb] = __builtin_amdgcn_mfma_f32_16x16x32_bf16(ah[mb], bl[nb], acc[mb][nb], 0, 0, 0);
                acc[mb][nb] = __builtin_amdgcn_mfma_f32_16x16x32_bf16(al[mb], bh[nb], acc[mb][nb], 0, 0, 0);
            }
        __syncthreads();
    }

#pragma unroll
    for (int mb = 0; mb < 4; ++mb)
#pragma unroll
        for (int nb = 0; nb < 4; ++nb) {
            int row = m0 + wm * 64 + mb * 16 + (lane >> 4) * 4;
            int col = n0 + wn * 64 + nb * 16 + (lane & 15);
#pragma unroll
            for (int r = 0; r < 4; ++r)
                C[(size_t)(row + r) * FF + col] = acc[mb][nb][r];
        }
}

// ---------------- kernel 3b: left GEMM, single bf16 product, bf16 out --------------
__global__ __launch_bounds__(256) void k_gemm_left(const ushort* __restrict__ Xh,
                                                   const ushort* __restrict__ Wb,
                                                   ushort* __restrict__ OutL) {
    const int comp = blockIdx.z;
    const ushort* A = Xh + (size_t)comp * BM_;
    const ushort* Bw = Wb + (size_t)(10 + GRADE_OF_C[comp]) * (FF * FF);
    ushort* C = OutL + (size_t)comp * BM_;
    const int m0 = blockIdx.x * 128;
    const int n0 = blockIdx.y * 128;

    __shared__ ushort As[128][32], Bs[128][32];

    const int tid = threadIdx.x;
    const int lane = tid & 63, wid = tid >> 6;
    const int wm = wid >> 1, wn = wid & 1;
    const int lr = lane & 15, lk = (lane >> 4) * 8;

    f32x4 acc[4][4] = {};

    for (int k0 = 0; k0 < FF; k0 += 32) {
#pragma unroll
        for (int pass = 0; pass < 2; ++pass) {
            int q = tid + pass * 256;
            int row = q >> 2;
            int col = (q & 3) * 8;
            *(uint4*)&As[row][col] = *(const uint4*)&A[(size_t)(m0 + row) * FF + k0 + col];
            *(uint4*)&Bs[row][col] = *(const uint4*)&Bw[(size_t)(n0 + row) * FF + k0 + col];
        }
        __syncthreads();
        bf16x8 af[4], bfr[4];
#pragma unroll
        for (int mb = 0; mb < 4; ++mb) af[mb] = *(const bf16x8*)&As[wm * 64 + mb * 16 + lr][lk];
#pragma unroll
        for (int nb = 0; nb < 4; ++nb) bfr[nb] = *(const bf16x8*)&Bs[wn * 64 + nb * 16 + lr][lk];
#pragma unroll
        for (int mb = 0; mb < 4; ++mb)
#pragma unroll
            for (int nb = 0; nb < 4; ++nb)
                acc[mb][nb] = __builtin_amdgcn_mfma_f32_16x16x32_bf16(af[mb], bfr[nb], acc[mb][nb], 0, 0, 0);
        __syncthreads();
    }

#pragma unroll
    for (int mb = 0; mb < 4; ++mb)
#pragma unroll
        for (int nb = 0; nb < 4; ++nb) {
            int row = m0 + wm * 64 + mb * 16 + (lane >> 4) * 4;
            int col = n0 + wn * 64 + nb * 16 + (lane & 15);
#pragma unroll
            for (int r = 0; r < 4; ++r)
                C[(size_t)(row + r) * FF + col] = f2bf(acc[mb][nb][r]);
        }
}

// ---------------- kernel 4: normalize(right) + Cayley gp + left + bias, scale ------
__global__ __launch_bounds__(256) void k_gp(const float* __restrict__ x,
                                            const float* __restrict__ OutR,
                                            const ushort* __restrict__ OutL,
                                            const float* __restrict__ gpw,
                                            const float* __restrict__ a_norm,
                                            const float* __restrict__ b_left,
                                            float* __restrict__ out) {
    const int bn = blockIdx.x * 256 + threadIdx.x;
    const int n = bn & (FF - 1);

    float xi[16];
    {
        const float4* xp = (const float4*)(x + (size_t)bn * 16);
#pragma unroll
        for (int j = 0; j < 4; ++j) {
            float4 t = xp[j];
            xi[j * 4 + 0] = t.x; xi[j * 4 + 1] = t.y; xi[j * 4 + 2] = t.z; xi[j * 4 + 3] = t.w;
        }
    }

    float R[16];
#pragma unroll
    for (int i = 0; i < 16; ++i) R[i] = OutR[(size_t)i * BM_ + bn];

    float q[5] = {0.f, 0.f, 0.f, 0.f, 0.f};
#pragma unroll
    for (int i = 0; i < 16; ++i) q[TBL.grade[i]] += TBL.beta[i] * R[i] * R[i];
    float inv[5];
#pragma unroll
    for (int g = 0; g < 5; ++g) {
        float nr = sqrtf(fabsf(q[g]));
        float a = a_norm[(size_t)n * 5 + g];
        float sig = 1.f / (1.f + __expf(-a));
        float nf = sig * (nr - 1.f) + 1.f + 1e-6f;
        inv[g] = 1.f / nf;
    }
#pragma unroll
    for (int i = 0; i < 16; ++i) R[i] *= inv[TBL.grade[i]];

    float pw[35];
#pragma unroll
    for (int p = 0; p < 35; ++p) pw[p] = gpw[(size_t)n * 35 + p];

    float acc[16] = {};
#pragma unroll
    for (int ii = 0; ii < 16; ++ii) {
#pragma unroll
        for (int kk = 0; kk < 16; ++kk) {
            const int j = TBL.jid[ii][kk];
            const int p = TBL.pid[ii][kk];
            const float s = TBL.sgn[ii][kk];
            acc[j] += (s * pw[p]) * (xi[ii] * R[kk]);
        }
    }

    const float bl = b_left[n];
    float o[16];
#pragma unroll
    for (int j = 0; j < 16; ++j) {
        float l = bf2f(OutL[(size_t)j * BM_ + bn]);
        if (j == 0) l += bl;
        o[j] = (l + acc[j]) * 0.70710678118654752440f;
    }
    float4* op = (float4*)(out + (size_t)bn * 16);
#pragma unroll
    for (int j = 0; j < 4; ++j) {
        float4 t;
        t.x = o[j * 4 + 0]; t.y = o[j * 4 + 1]; t.z = o[j * 4 + 2]; t.w = o[j * 4 + 3];
        op[j] = t;
    }
}

extern "C" void kernel_launch(void* const* d_in, const int* in_sizes, int n_in,
                              void* d_out, int out_size, void* d_ws, size_t ws_size,
                              hipStream_t stream) {
    (void)in_sizes; (void)n_in; (void)out_size; (void)ws_size;
    const float* x       = (const float*)d_in[0];
    const float* w_left  = (const float*)d_in[1];
    const float* b_left  = (const float*)d_in[2];
    const float* w_right = (const float*)d_in[3];
    const float* a_norm  = (const float*)d_in[4];
    const float* gpw     = (const float*)d_in[5];
    float* out = (float*)d_out;

    // workspace: Xh 64MB | Xl 64MB | Wb 7.5MB | OutR 134MB (f32) | OutL 64MB (bf16)
    char* ws = (char*)d_ws;
    ushort* Xh   = (ushort*)ws;                                   //  67,108,864 B
    ushort* Xl   = (ushort*)(ws + 67108864);                      //  67,108,864 B
    ushort* Wb   = (ushort*)(ws + 134217728);                     //   7,864,320 B
    float*  OutR = (float*)(ws + 142082048);                      // 134,217,728 B
    ushort* OutL = (ushort*)(ws + 276299776);                     //  67,108,864 B
    // total 343,408,640 B

    k_transpose_x<<<4096, 256, 0, stream>>>(x, Xh, Xl);
    k_prep_w<<<512, 256, 0, stream>>>(w_right, w_left, Wb);
    dim3 g(32, 4, 16);
    k_gemm_right<<<g, 256, 0, stream>>>(Xh, Xl, Wb, OutR);
    k_gemm_left<<<g, 256, 0, stream>>>(Xh, Wb, OutL);
    k_gp<<<8192, 256, 0, stream>>>(x, OutR, OutL, gpw, a_norm, b_left, out);
}

// Round 3
// 367.410 us; speedup vs baseline: 1.1054x; 1.1054x over previous
//
#include <hip/hip_runtime.h>

typedef unsigned int uint;
typedef unsigned short ushort;
typedef __attribute__((ext_vector_type(8))) short bf16x8;
typedef __attribute__((ext_vector_type(4))) float f32x4;

// ---------------- compile-time Clifford tables (replicates reference numpy) --------
struct GPTables {
    signed char jid[16][16];
    float       sgn[16][16];
    signed char pid[16][16];
    float       beta[16];
    signed char grade[16];
};

constexpr int popc4(int x) { return ((x >> 0) & 1) + ((x >> 1) & 1) + ((x >> 2) & 1) + ((x >> 3) & 1); }

constexpr GPTables make_tables() {
    GPTables T{};
    int blades[16] = {0, 1, 2, 4, 8, 3, 5, 6, 9, 10, 12, 7, 11, 13, 14, 15};
    int idxof[16] = {};
    for (int i = 0; i < 16; ++i) idxof[blades[i]] = i;
    float metric[4] = {1.f, -1.f, -1.f, -1.f};
    for (int i = 0; i < 16; ++i) {
        T.grade[i] = (signed char)popc4(blades[i]);
        float b = 1.f;
        for (int bit = 0; bit < 4; ++bit)
            if ((blades[i] >> bit) & 1) b *= metric[bit];
        T.beta[i] = b;
    }
    bool paths[5][5][5] = {};
    for (int a = 0; a < 16; ++a)
        for (int b = 0; b < 16; ++b)
            paths[popc4(a)][popc4(a ^ b)][popc4(b)] = true;
    int pid3[5][5][5] = {};
    int cnt = 0;
    for (int gi = 0; gi < 5; ++gi)
        for (int gj = 0; gj < 5; ++gj)
            for (int gk = 0; gk < 5; ++gk)
                if (paths[gi][gj][gk]) pid3[gi][gj][gk] = cnt++;
    for (int ii = 0; ii < 16; ++ii) {
        for (int kk = 0; kk < 16; ++kk) {
            int a = blades[ii], b = blades[kk];
            int c = a ^ b;
            int s = 0, t = a >> 1;
            while (t) { s += popc4(t & b); t >>= 1; }
            float sign = (s & 1) ? -1.f : 1.f;
            for (int bit = 0; bit < 4; ++bit)
                if (((a >> bit) & 1) && ((b >> bit) & 1)) sign *= metric[bit];
            T.jid[ii][kk] = (signed char)idxof[c];
            T.sgn[ii][kk] = sign;
            T.pid[ii][kk] = (signed char)pid3[popc4(a)][popc4(c)][popc4(b)];
        }
    }
    return T;
}

constexpr GPTables TBL = make_tables();

// sizes
#define BF (4096)
#define FF (512)
#define BM_ (2097152)   // BF*FF
#define FFFF (262144)   // FF*FF

__device__ inline ushort f2bf(float f) {
    uint u = __float_as_uint(f);
    uint r = (u + 0x7fffu + ((u >> 16) & 1u)) >> 16;
    return (ushort)r;
}
__device__ inline float bf2f(ushort h) { return __uint_as_float(((uint)h) << 16); }

typedef __attribute__((address_space(3))) uint lds_u32;
typedef const __attribute__((address_space(1))) uint g_u32;
__device__ __forceinline__ void gload16(const void* gsrc, void* ldst) {
    __builtin_amdgcn_global_load_lds((g_u32*)gsrc, (lds_u32*)ldst, 16, 0, 0);
}

// ---------------- kernel 1: transpose + split-cast x -> Xh/Xl [16][BM_] ------------
__global__ __launch_bounds__(256) void k_transpose_x(const float* __restrict__ x,
                                                     ushort* __restrict__ Xh,
                                                     ushort* __restrict__ Xl) {
    const int p0 = (blockIdx.x * 256 + threadIdx.x) * 2;
    float v[32];
    const float4* x4 = (const float4*)(x + (size_t)p0 * 16);
#pragma unroll
    for (int j = 0; j < 8; ++j) {
        float4 t = x4[j];
        v[j * 4 + 0] = t.x; v[j * 4 + 1] = t.y; v[j * 4 + 2] = t.z; v[j * 4 + 3] = t.w;
    }
#pragma unroll
    for (int i = 0; i < 16; ++i) {
        ushort h0 = f2bf(v[i]),      h1 = f2bf(v[16 + i]);
        ushort l0 = f2bf(v[i] - bf2f(h0));
        ushort l1 = f2bf(v[16 + i] - bf2f(h1));
        *(uint*)&Xh[(size_t)i * BM_ + p0] = (uint)h0 | ((uint)h1 << 16);
        *(uint*)&Xl[(size_t)i * BM_ + p0] = (uint)l0 | ((uint)l1 << 16);
    }
}

// ---------------- kernel 2: pack weights -> Wb[15][512][512] bf16 ------------------
// planes 0..4 right_hi, 5..9 right_lo, 10..14 left (per grade)
__global__ __launch_bounds__(256) void k_prep_w(const float* __restrict__ w_right,
                                                const float* __restrict__ w_left,
                                                ushort* __restrict__ Wb) {
    const int n = blockIdx.x;
    const int m = threadIdx.x * 2;
#pragma unroll
    for (int g = 0; g < 5; ++g) {
        float a = w_right[(size_t)n * (FF * 5) + (size_t)m * 5 + g];
        float b = w_right[(size_t)n * (FF * 5) + (size_t)(m + 1) * 5 + g];
        ushort ah = f2bf(a), bh = f2bf(b);
        ushort al = f2bf(a - bf2f(ah)), bl = f2bf(b - bf2f(bh));
        *(uint*)&Wb[(size_t)g * FFFF + (size_t)n * FF + m] = (uint)ah | ((uint)bh << 16);
        *(uint*)&Wb[(size_t)(5 + g) * FFFF + (size_t)n * FF + m] = (uint)al | ((uint)bl << 16);
        float c = w_left[(size_t)n * (FF * 5) + (size_t)m * 5 + g];
        float d = w_left[(size_t)n * (FF * 5) + (size_t)(m + 1) * 5 + g];
        *(uint*)&Wb[(size_t)(10 + g) * FFFF + (size_t)n * FF + m] =
            (uint)f2bf(c) | ((uint)f2bf(d) << 16);
    }
}

// ---------------- kernel 3: merged GEMM (right split-bf16 + left) ------------------
// grid (32,4,16): per block one 128x128 tile of one comp; computes
//   OutR[comp][b][n] (f32, 3 MFMA products) and OutL[comp][b][n] (bf16, 1 product)
__device__ __forceinline__ bf16x8 ldfrag(const ushort* tile, int row, int colb) {
    return *(const bf16x8*)((const char*)tile + row * 64 + (colb ^ ((row & 3) << 4)));
}

__global__ __launch_bounds__(256, 2) void k_gemm(const ushort* __restrict__ Xh,
                                                 const ushort* __restrict__ Xl,
                                                 const ushort* __restrict__ Wb,
                                                 float* __restrict__ OutR,
                                                 ushort* __restrict__ OutL) {
    const int comp = blockIdx.z;
    const int g = TBL.grade[comp];
    const ushort* Ah = Xh + (size_t)comp * BM_;
    const ushort* Al = Xl + (size_t)comp * BM_;
    const ushort* Bh = Wb + (size_t)g * FFFF;
    const ushort* Bl = Wb + (size_t)(5 + g) * FFFF;
    const ushort* BL = Wb + (size_t)(10 + g) * FFFF;
    const int m0 = blockIdx.x * 128;
    const int n0 = blockIdx.y * 128;

    // 5 tiles x [128][32] bf16 = 40KB, linear dest for global_load_lds,
    // source pre-swizzled so reads can XOR-swizzle (bank-conflict-free-ish)
    __shared__ ushort sh[5 * 128 * 32];
    ushort* tA  = sh;
    ushort* tAl = sh + 1 * 4096;
    ushort* tBh = sh + 2 * 4096;
    ushort* tBl = sh + 3 * 4096;
    ushort* tBL = sh + 4 * 4096;

    const int tid = threadIdx.x;
    const int lane = tid & 63, wid = tid >> 6;
    const int wm = wid >> 1, wn = wid & 1;
    const int lr = lane & 15;
    const int kb = (lane >> 4) * 16;  // byte col of 16B k-slice

    f32x4 accR[4][4] = {};
    f32x4 accL[4][4] = {};

    for (int k0 = 0; k0 < FF; k0 += 32) {
#pragma unroll
        for (int pass = 0; pass < 2; ++pass) {
            const int c = tid + pass * 256;       // 0..511 chunk id
            const int row = c >> 2;
            const int scb = ((c & 3) * 16) ^ ((row & 3) << 4);  // pre-swizzled src col
            const size_t gb = (size_t)row * (FF * 2) + (size_t)k0 * 2 + scb;
            const size_t mb_ = (size_t)m0 * (FF * 2), nb_ = (size_t)n0 * (FF * 2);
            char* dst = (char*)sh + c * 16;
            gload16((const char*)Ah + mb_ + gb, dst);
            gload16((const char*)Al + mb_ + gb, dst + 8192);
            gload16((const char*)Bh + nb_ + gb, dst + 16384);
            gload16((const char*)Bl + nb_ + gb, dst + 24576);
            gload16((const char*)BL + nb_ + gb, dst + 32768);
        }
        __syncthreads();
        bf16x8 ah[4], al[4], bh[4], bl[4], bLf[4];
#pragma unroll
        for (int mb = 0; mb < 4; ++mb) {
            ah[mb] = ldfrag(tA,  wm * 64 + mb * 16 + lr, kb);
            al[mb] = ldfrag(tAl, wm * 64 + mb * 16 + lr, kb);
        }
#pragma unroll
        for (int nb = 0; nb < 4; ++nb) {
            bh[nb]  = ldfrag(tBh, wn * 64 + nb * 16 + lr, kb);
            bl[nb]  = ldfrag(tBl, wn * 64 + nb * 16 + lr, kb);
            bLf[nb] = ldfrag(tBL, wn * 64 + nb * 16 + lr, kb);
        }
#pragma unroll
        for (int mb = 0; mb < 4; ++mb)
#pragma unroll
            for (int nb = 0; nb < 4; ++nb) {
                accR[mb][nb] = __builtin_amdgcn_mfma_f32_16x16x32_bf16(ah[mb], bh[nb],  accR[mb][nb], 0, 0, 0);
                accR[mb][nb] = __builtin_amdgcn_mfma_f32_16x16x32_bf16(ah[mb], bl[nb],  accR[mb][nb], 0, 0, 0);
                accR[mb][nb] = __builtin_amdgcn_mfma_f32_16x16x32_bf16(al[mb], bh[nb],  accR[mb][nb], 0, 0, 0);
                accL[mb][nb] = __builtin_amdgcn_mfma_f32_16x16x32_bf16(ah[mb], bLf[nb], accL[mb][nb], 0, 0, 0);
            }
        __syncthreads();
    }

    float* CR = OutR + (size_t)comp * BM_;
    ushort* CL = OutL + (size_t)comp * BM_;
#pragma unroll
    for (int mb = 0; mb < 4; ++mb)
#pragma unroll
        for (int nb = 0; nb < 4; ++nb) {
            int row = m0 + wm * 64 + mb * 16 + (lane >> 4) * 4;
            int col = n0 + wn * 64 + nb * 16 + (lane & 15);
#pragma unroll
            for (int r = 0; r < 4; ++r) {
                CR[(size_t)(row + r) * FF + col] = accR[mb][nb][r];
                CL[(size_t)(row + r) * FF + col] = f2bf(accL[mb][nb][r]);
            }
        }
}

// ---------------- kernel 4: normalize(right) + Cayley gp + left + bias, scale ------
__global__ __launch_bounds__(256) void k_gp(const float* __restrict__ x,
                                            const float* __restrict__ OutR,
                                            const ushort* __restrict__ OutL,
                                            const float* __restrict__ gpw,
                                            const float* __restrict__ a_norm,
                                            const float* __restrict__ b_left,
                                            float* __restrict__ out) {
    __shared__ float s_pw[256 * 35];
    __shared__ float s_an[256 * 5];
    __shared__ float s_bl[256];

    const int tid = threadIdx.x;
    const int bn = blockIdx.x * 256 + tid;
    const int n0 = (blockIdx.x & 1) * 256;  // block's 256 consecutive n

    for (int i = tid; i < 256 * 35; i += 256) s_pw[i] = gpw[(size_t)n0 * 35 + i];
#pragma unroll
    for (int i = 0; i < 5; ++i) s_an[tid + i * 256] = a_norm[(size_t)n0 * 5 + tid + i * 256];
    s_bl[tid] = b_left[n0 + tid];
    __syncthreads();

    float xi[16];
    {
        const float4* xp = (const float4*)(x + (size_t)bn * 16);
#pragma unroll
        for (int j = 0; j < 4; ++j) {
            float4 t = xp[j];
            xi[j * 4 + 0] = t.x; xi[j * 4 + 1] = t.y; xi[j * 4 + 2] = t.z; xi[j * 4 + 3] = t.w;
        }
    }

    float R[16];
#pragma unroll
    for (int i = 0; i < 16; ++i) R[i] = OutR[(size_t)i * BM_ + bn];

    float q[5] = {0.f, 0.f, 0.f, 0.f, 0.f};
#pragma unroll
    for (int i = 0; i < 16; ++i) q[TBL.grade[i]] += TBL.beta[i] * R[i] * R[i];
    float inv[5];
#pragma unroll
    for (int g = 0; g < 5; ++g) {
        float nr = sqrtf(fabsf(q[g]));
        float a = s_an[tid * 5 + g];
        float sig = 1.f / (1.f + __expf(-a));
        float nf = sig * (nr - 1.f) + 1.f + 1e-6f;
        inv[g] = 1.f / nf;
    }
#pragma unroll
    for (int i = 0; i < 16; ++i) R[i] *= inv[TBL.grade[i]];

    float pw[35];
#pragma unroll
    for (int p = 0; p < 35; ++p) pw[p] = s_pw[tid * 35 + p];

    float acc[16] = {};
#pragma unroll
    for (int ii = 0; ii < 16; ++ii) {
#pragma unroll
        for (int kk = 0; kk < 16; ++kk) {
            const int j = TBL.jid[ii][kk];
            const int p = TBL.pid[ii][kk];
            const float s = TBL.sgn[ii][kk];
            acc[j] += (s * pw[p]) * (xi[ii] * R[kk]);
        }
    }

    const float bl = s_bl[tid];
    float o[16];
#pragma unroll
    for (int j = 0; j < 16; ++j) {
        float l = bf2f(OutL[(size_t)j * BM_ + bn]);
        if (j == 0) l += bl;
        o[j] = (l + acc[j]) * 0.70710678118654752440f;
    }
    float4* op = (float4*)(out + (size_t)bn * 16);
#pragma unroll
    for (int j = 0; j < 4; ++j) {
        float4 t;
        t.x = o[j * 4 + 0]; t.y = o[j * 4 + 1]; t.z = o[j * 4 + 2]; t.w = o[j * 4 + 3];
        op[j] = t;
    }
}

extern "C" void kernel_launch(void* const* d_in, const int* in_sizes, int n_in,
                              void* d_out, int out_size, void* d_ws, size_t ws_size,
                              hipStream_t stream) {
    (void)in_sizes; (void)n_in; (void)out_size; (void)ws_size;
    const float* x       = (const float*)d_in[0];
    const float* w_left  = (const float*)d_in[1];
    const float* b_left  = (const float*)d_in[2];
    const float* w_right = (const float*)d_in[3];
    const float* a_norm  = (const float*)d_in[4];
    const float* gpw     = (const float*)d_in[5];
    float* out = (float*)d_out;

    char* ws = (char*)d_ws;
    ushort* Xh   = (ushort*)ws;                        //  67,108,864 B
    ushort* Xl   = (ushort*)(ws + 67108864);           //  67,108,864 B
    ushort* Wb   = (ushort*)(ws + 134217728);          //   7,864,320 B
    float*  OutR = (float*)(ws + 142082048);           // 134,217,728 B
    ushort* OutL = (ushort*)(ws + 276299776);          //  67,108,864 B

    k_transpose_x<<<4096, 256, 0, stream>>>(x, Xh, Xl);
    k_prep_w<<<512, 256, 0, stream>>>(w_right, w_left, Wb);
    dim3 g(32, 4, 16);
    k_gemm<<<g, 256, 0, stream>>>(Xh, Xl, Wb, OutR, OutL);
    k_gp<<<8192, 256, 0, stream>>>(x, OutR, OutL, gpw, a_norm, b_left, out);
}